// Round 3
// baseline (154.397 us; speedup 1.0000x reference)
//
#include <hip/hip_runtime.h>

// CoreAttention: causal flash attention fwd. B=2,H=16,S=2048,D=64, fp32 in/out.
// R8: R7 split-KV with the mode-0 mapping bug fixed. R7 used i=47-xid for the
// full-tile branch (duplicating split tiles 16..31 and never computing 0..15);
// correct heavy-first mapping is i=31-xid. Design unchanged: fixed-shift
// softmax => kv-split partials combine LINEARLY: O=(O_A+O_B)/(l_A+l_B).
// q-tiles 16..31 split into chunk A (kv 0..15, unmasked, partial->ws) and
// chunk B (kv 16..i, masked, partial->O); combine finalizes rows 1024..2047.
// Max sequential chain 32 -> 16 tiles; grid 1536 blocks; single-buffer LDS
// 18.4 KB; launch_bounds(128,4). Compute core unchanged.

#define S_LEN 2048
#define D_DIM 64
#define QSCALE 0.1803368867f          // (1/8) * log2(e)
#define CSHIFT 23.0831206542f         // 16 * log2(e): fixed-shift softmax (shift-invariant)
#define BHSTR 131072                  // shorts per bh plane (2048*64)

typedef __attribute__((ext_vector_type(8))) short short8;
typedef __attribute__((ext_vector_type(4))) short short4v;
typedef __attribute__((ext_vector_type(4))) float float4v;

typedef const __attribute__((address_space(1))) void cg_void;
typedef __attribute__((address_space(3))) void lds_void;

__device__ __forceinline__ short f2bf(float x) {
    union { float f; unsigned u; } c; c.f = x;
    unsigned u = c.u + 0x7fffu + ((c.u >> 16) & 1u);
    return (short)(u >> 16);
}

#if __has_builtin(__builtin_amdgcn_mfma_f32_16x16x16_bf16)
__device__ __forceinline__ float4v mfma16(short4v a, short4v b, float4v c) {
    return __builtin_amdgcn_mfma_f32_16x16x16_bf16(a, b, c, 0, 0, 0);
}
#elif __has_builtin(__builtin_amdgcn_mfma_f32_16x16x16bf16_1k)
__device__ __forceinline__ float4v mfma16(short4v a, short4v b, float4v c) {
    return __builtin_amdgcn_mfma_f32_16x16x16bf16_1k(a, b, c, 0, 0, 0);
}
#else
__device__ __forceinline__ float4v mfma16(short4v a, short4v b, float4v c) {
    float4v d;
    asm("v_mfma_f32_16x16x16_bf16 %0, %1, %2, %3"
        : "=v"(d) : "v"(a), "v"(b), "0"(c));
    return d;
}
#endif

// ---------------- pre-pass: K -> bf16 copy, V -> bf16 transposed (R2 layout) ----------------
#define PVS 80
__global__ __launch_bounds__(256, 4)
void prep(const float* __restrict__ K, const float* __restrict__ V,
          short* __restrict__ Kbf, short* __restrict__ Vt) {
    __shared__ __align__(16) short Vl[D_DIM * PVS];
    const int tid = threadIdx.x;
    const int st  = blockIdx.x;
    const int bh  = blockIdx.y;
    const size_t base = ((size_t)bh * S_LEN + st * 64) * D_DIM;

    #pragma unroll
    for (int i = 0; i < 4; ++i) {
        const int e = (i * 256 + tid) * 4;
        const int kv = e >> 6, d0 = e & 63;
        float4v k4 = *(const float4v*)(K + base + e);
        short4v ks = { f2bf(k4.x), f2bf(k4.y), f2bf(k4.z), f2bf(k4.w) };
        *(short4v*)(Kbf + base + e) = ks;
        float4v v4 = *(const float4v*)(V + base + e);
        Vl[(d0 + 0) * PVS + kv] = f2bf(v4.x);
        Vl[(d0 + 1) * PVS + kv] = f2bf(v4.y);
        Vl[(d0 + 2) * PVS + kv] = f2bf(v4.z);
        Vl[(d0 + 3) * PVS + kv] = f2bf(v4.w);
    }
    __syncthreads();
    const int d = tid >> 2, c = tid & 3;
    short8 a = *(const short8*)&Vl[d * PVS + c * 16];
    short8 b = *(const short8*)&Vl[d * PVS + c * 16 + 8];
    short* dst = Vt + (size_t)bh * BHSTR + (size_t)d * S_LEN + st * 64 + c * 16;
    *(short8*)dst = a;
    *(short8*)(dst + 8) = b;
}

// ---------------- hot kernel (split-KV) ----------------
// blockIdx.x in [0,48):
//   [0,16):  mode 1, A-chunk of q-tile i=16+xid, kv tiles [0,16), never masked,
//            unnormalized partial -> OA ws + lA.
//   [16,32): mode 0, full q-tile i=31-xid (15..0), kv tiles [0,i], masked,
//            final normalized O store.
//   [32,48): mode 2, B-chunk of q-tile i=63-xid (31..16), kv tiles [16,i],
//            masked, unnormalized partial -> O + lB.
// Heavy blocks map to low blockIdx.x (dispatch-first).
// LDS single buffer: 1152 slots x 16B = 18432 B.
__global__ __launch_bounds__(128, 4)
void fa_fwd8(const float* __restrict__ Q, const short* __restrict__ Kbf,
             const short* __restrict__ Vt, float* __restrict__ O,
             float* __restrict__ OA, float* __restrict__ lab) {
    __shared__ __align__(16) short SB[9216];

    const int tid  = threadIdx.x;       // 0..127, 2 waves
    const int w    = tid >> 6;
    const int lane = tid & 63;
    const int l15  = lane & 15;
    const int quad = lane >> 4;

    const int bh  = blockIdx.y;
    const int xid = blockIdx.x;
    int i, t0, t1, mode;
    if (xid < 16)      { i = 16 + xid;  t0 = 0;  t1 = 16;    mode = 1; }
    else if (xid < 32) { i = 31 - xid;  t0 = 0;  t1 = i + 1; mode = 0; }   // 15..0
    else               { i = 63 - xid;  t0 = 16; t1 = i + 1; mode = 2; }   // 31..16
    const int q0 = i * 64;

    const float* Qb  = Q + (size_t)bh * S_LEN * D_DIM;
    const short* KbB = Kbf + (size_t)bh * BHSTR;
    const short* VtB = Vt  + (size_t)bh * BHSTR;
    float*       Ob  = O + (size_t)bh * S_LEN * D_DIM;

    // staging: 9 slots/thread (1152 = 9*128). Slot s = i*128 + tid.
    const short* gsrc[9]; int gcoef[9];
    #pragma unroll
    for (int ii = 0; ii < 9; ++ii) {
        const int s = ii * 128 + tid;
        if (s < 576) {
            const int row = s / 9, j = s - row * 9;
            const int j8 = (j == 8) ? 0 : j;        // dup into pad chunk (never read)
            gsrc[ii] = KbB + row * 64 + j8 * 8;
            gcoef[ii] = 4096;
        } else {
            const int ss = s - 576;
            const int row = ss / 9, j = ss - row * 9;
            const int j8 = (j == 8) ? 7 : j;
            gsrc[ii] = VtB + (size_t)row * S_LEN + j8 * 8;
            gcoef[ii] = 64;
        }
    }

    // Q B-frags: B[k=d=quad*8+j(+32c)][n=q=l15], scale log2e/8 folded. 2 q-tiles/wave.
    short8 qfrag[2][2];
    #pragma unroll
    for (int qt = 0; qt < 2; ++qt) {
        const float* qp = Qb + (size_t)(q0 + (w * 2 + qt) * 16 + l15) * D_DIM;
        #pragma unroll
        for (int c = 0; c < 2; ++c) {
            const int d0 = c * 32 + quad * 8;
            float4v a = *(const float4v*)(qp + d0);
            float4v b = *(const float4v*)(qp + d0 + 4);
            qfrag[qt][c][0] = f2bf(a.x * QSCALE); qfrag[qt][c][1] = f2bf(a.y * QSCALE);
            qfrag[qt][c][2] = f2bf(a.z * QSCALE); qfrag[qt][c][3] = f2bf(a.w * QSCALE);
            qfrag[qt][c][4] = f2bf(b.x * QSCALE); qfrag[qt][c][5] = f2bf(b.y * QSCALE);
            qfrag[qt][c][6] = f2bf(b.z * QSCALE); qfrag[qt][c][7] = f2bf(b.w * QSCALE);
        }
    }

    float l_lane[2] = {0.f, 0.f};
    float4v o_acc[2][4];
    #pragma unroll
    for (int qt = 0; qt < 2; ++qt)
        #pragma unroll
        for (int td = 0; td < 4; ++td) o_acc[qt][td] = (float4v)0.0f;

    const short* Ks = SB;
    const short* Vs = SB + 4608;

    for (int t = t0; t < t1; ++t) {
        __syncthreads();   // prior iteration's ds_reads done; LDS reusable
        #pragma unroll
        for (int ii = 0; ii < 9; ++ii)
            __builtin_amdgcn_global_load_lds(
                (cg_void*)(gsrc[ii] + (size_t)t * gcoef[ii]),
                (lds_void*)&SB[ii * 1024 + w * 512],   // wave-uniform base; HW adds lane*16
                16, 0, 0);
        __syncthreads();   // vmcnt(0) drain -> tile resident

        // S^T = K Q^T: A = K-frag (LDS), B = Q-frag (regs). sc[qt][tt][r]=S^T[kv][q=l15]
        float4v sc[2][4];
        #pragma unroll
        for (int tt = 0; tt < 4; ++tt) {
            const short* kr = &Ks[(tt * 16 + l15) * 72 + quad * 8];
            short8 k0 = *(const short8*)(kr);
            short8 k1 = *(const short8*)(kr + 32);
            #pragma unroll
            for (int qt = 0; qt < 2; ++qt) {
                float4v acc = (float4v)0.0f;
                acc = __builtin_amdgcn_mfma_f32_16x16x32_bf16(k0, qfrag[qt][0], acc, 0, 0, 0);
                acc = __builtin_amdgcn_mfma_f32_16x16x32_bf16(k1, qfrag[qt][1], acc, 0, 0, 0);
                sc[qt][tt] = acc;
            }
        }

        if (t == i) {   // causal mask, diagonal tile only (never true in mode 1)
            #pragma unroll
            for (int qt = 0; qt < 2; ++qt) {
                const int qrow = q0 + (w * 2 + qt) * 16 + l15;
                #pragma unroll
                for (int tt = 0; tt < 4; ++tt) {
                    const int kv = t * 64 + tt * 16 + quad * 4;
                    #pragma unroll
                    for (int r = 0; r < 4; ++r)
                        if (kv + r > qrow) sc[qt][tt][r] = -3.0e38f;
                }
            }
        }

        // fixed-shift softmax numerator + pack P^T bf16 B-frags (register path)
        short4v pb[2][4];
        #pragma unroll
        for (int qt = 0; qt < 2; ++qt)
            #pragma unroll
            for (int tt = 0; tt < 4; ++tt) {
                #pragma unroll
                for (int r = 0; r < 4; ++r) {
                    float p = __builtin_amdgcn_exp2f(sc[qt][tt][r] - CSHIFT);
                    sc[qt][tt][r] = p;
                    l_lane[qt] += p;
                }
                pb[qt][tt] = short4v{ f2bf(sc[qt][tt][0]), f2bf(sc[qt][tt][1]),
                                      f2bf(sc[qt][tt][2]), f2bf(sc[qt][tt][3]) };
            }

        // O^T += V^T P^T: A = V^T frag (LDS b64), B = P^T (regs). Each va feeds 2 MFMAs.
        #pragma unroll
        for (int td = 0; td < 4; ++td) {
            const short* vr = &Vs[(td * 16 + l15) * 72 + quad * 4];
            #pragma unroll
            for (int tt = 0; tt < 4; ++tt) {
                short4v va = *(const short4v*)(vr + tt * 16);
                #pragma unroll
                for (int qt = 0; qt < 2; ++qt)
                    o_acc[qt][td] = mfma16(va, pb[qt][tt], o_acc[qt][td]);
            }
        }
    }

    // epilogue: reduce l across quads (same column q=l15); store per mode
    #pragma unroll
    for (int qt = 0; qt < 2; ++qt) {
        float l = l_lane[qt];
        l += __shfl_xor(l, 16);
        l += __shfl_xor(l, 32);
        const int qrow = q0 + (w * 2 + qt) * 16 + l15;
        if (mode == 0) {
            const float inv = 1.0f / l;
            float* op = Ob + (size_t)qrow * D_DIM + quad * 4;
            #pragma unroll
            for (int td = 0; td < 4; ++td) {
                float4v st = { o_acc[qt][td][0] * inv, o_acc[qt][td][1] * inv,
                               o_acc[qt][td][2] * inv, o_acc[qt][td][3] * inv };
                *(float4v*)(op + td * 16) = st;
            }
        } else {
            const int rloc = qrow - 1024;         // [0,1024)
            float* op = (mode == 2)
                ? (Ob + (size_t)qrow * D_DIM + quad * 4)
                : (OA + ((size_t)bh * 1024 + rloc) * D_DIM + quad * 4);
            #pragma unroll
            for (int td = 0; td < 4; ++td)
                *(float4v*)(op + td * 16) = o_acc[qt][td];
            if (quad == 0)
                lab[(mode == 1 ? 0 : 32768) + bh * 1024 + rloc] = l;
        }
    }
}

// ---------------- combine: rows 1024..2047 per bh: O = (O + OA)/(lA+lB) ----------------
__global__ __launch_bounds__(256, 4)
void combine(float* __restrict__ O, const float* __restrict__ OA,
             const float* __restrict__ lab) {
    const int bh = blockIdx.y;
    const int g  = blockIdx.x * 256 + threadIdx.x;   // [0, 16384) float4s per bh
    const int row = g >> 4;                           // [0,1024)
    const int d4  = (g & 15) * 4;
    const float l = lab[bh * 1024 + row] + lab[32768 + bh * 1024 + row];
    const float inv = 1.0f / l;
    float4v a = *(const float4v*)(OA + ((size_t)bh * 1024 + row) * D_DIM + d4);
    float* op = O + ((size_t)bh * S_LEN + 1024 + row) * D_DIM + d4;
    float4v o = *(const float4v*)op;
    float4v r = { (o[0] + a[0]) * inv, (o[1] + a[1]) * inv,
                  (o[2] + a[2]) * inv, (o[3] + a[3]) * inv };
    *(float4v*)op = r;
}

// ---------------- mid fallback: R6 double-buffer, unsplit (ws in [16.8,25.4) MB) ----------------
__global__ __launch_bounds__(128, 2)
void fa_fwd6(const float* __restrict__ Q, const short* __restrict__ Kbf,
             const short* __restrict__ Vt, float* __restrict__ O) {
    __shared__ __align__(16) short SB[18432];

    const int tid  = threadIdx.x;
    const int w    = tid >> 6;
    const int lane = tid & 63;
    const int l15  = lane & 15;
    const int quad = lane >> 4;

    const int bh  = blockIdx.y;
    const int blk = gridDim.x - 1 - blockIdx.x;
    const int q0  = blk * 64;

    const float* Qb  = Q + (size_t)bh * S_LEN * D_DIM;
    const short* KbB = Kbf + (size_t)bh * BHSTR;
    const short* VtB = Vt  + (size_t)bh * BHSTR;
    float*       Ob  = O + (size_t)bh * S_LEN * D_DIM;

    const short* gsrc[9]; int gcoef[9];
    #pragma unroll
    for (int i = 0; i < 9; ++i) {
        const int s = i * 128 + tid;
        if (s < 576) {
            const int row = s / 9, j = s - row * 9;
            const int j8 = (j == 8) ? 0 : j;
            gsrc[i] = KbB + row * 64 + j8 * 8;
            gcoef[i] = 4096;
        } else {
            const int ss = s - 576;
            const int row = ss / 9, j = ss - row * 9;
            const int j8 = (j == 8) ? 7 : j;
            gsrc[i] = VtB + (size_t)row * S_LEN + j8 * 8;
            gcoef[i] = 64;
        }
    }

    short8 qfrag[2][2];
    #pragma unroll
    for (int qt = 0; qt < 2; ++qt) {
        const float* qp = Qb + (size_t)(q0 + (w * 2 + qt) * 16 + l15) * D_DIM;
        #pragma unroll
        for (int c = 0; c < 2; ++c) {
            const int d0 = c * 32 + quad * 8;
            float4v a = *(const float4v*)(qp + d0);
            float4v b = *(const float4v*)(qp + d0 + 4);
            qfrag[qt][c][0] = f2bf(a.x * QSCALE); qfrag[qt][c][1] = f2bf(a.y * QSCALE);
            qfrag[qt][c][2] = f2bf(a.z * QSCALE); qfrag[qt][c][3] = f2bf(a.w * QSCALE);
            qfrag[qt][c][4] = f2bf(b.x * QSCALE); qfrag[qt][c][5] = f2bf(b.y * QSCALE);
            qfrag[qt][c][6] = f2bf(b.z * QSCALE); qfrag[qt][c][7] = f2bf(b.w * QSCALE);
        }
    }

    float l_lane[2] = {0.f, 0.f};
    float4v o_acc[2][4];
    #pragma unroll
    for (int qt = 0; qt < 2; ++qt)
        #pragma unroll
        for (int td = 0; td < 4; ++td) o_acc[qt][td] = (float4v)0.0f;

    const int n_tiles = blk + 1;

    #pragma unroll
    for (int i = 0; i < 9; ++i)
        __builtin_amdgcn_global_load_lds(
            (cg_void*)gsrc[i], (lds_void*)&SB[i * 1024 + w * 512], 16, 0, 0);
    __syncthreads();

    for (int t = 0; t < n_tiles; ++t) {
        const int cur = (t & 1) * 9216;
        if (t + 1 < n_tiles) {
            const int nxt = 9216 - cur;
            #pragma unroll
            for (int i = 0; i < 9; ++i) {
                gsrc[i] += gcoef[i];
                __builtin_amdgcn_global_load_lds(
                    (cg_void*)gsrc[i], (lds_void*)&SB[nxt + i * 1024 + w * 512], 16, 0, 0);
            }
        }
        const short* Ks = SB + cur;
        const short* Vs = SB + cur + 4608;

        float4v sc[2][4];
        #pragma unroll
        for (int tt = 0; tt < 4; ++tt) {
            const short* kr = &Ks[(tt * 16 + l15) * 72 + quad * 8];
            short8 k0 = *(const short8*)(kr);
            short8 k1 = *(const short8*)(kr + 32);
            #pragma unroll
            for (int qt = 0; qt < 2; ++qt) {
                float4v acc = (float4v)0.0f;
                acc = __builtin_amdgcn_mfma_f32_16x16x32_bf16(k0, qfrag[qt][0], acc, 0, 0, 0);
                acc = __builtin_amdgcn_mfma_f32_16x16x32_bf16(k1, qfrag[qt][1], acc, 0, 0, 0);
                sc[qt][tt] = acc;
            }
        }

        if (t == blk) {
            #pragma unroll
            for (int qt = 0; qt < 2; ++qt) {
                const int qrow = q0 + (w * 2 + qt) * 16 + l15;
                #pragma unroll
                for (int tt = 0; tt < 4; ++tt) {
                    const int kv = t * 64 + tt * 16 + quad * 4;
                    #pragma unroll
                    for (int r = 0; r < 4; ++r)
                        if (kv + r > qrow) sc[qt][tt][r] = -3.0e38f;
                }
            }
        }

        short4v pb[2][4];
        #pragma unroll
        for (int qt = 0; qt < 2; ++qt)
            #pragma unroll
            for (int tt = 0; tt < 4; ++tt) {
                #pragma unroll
                for (int r = 0; r < 4; ++r) {
                    float p = __builtin_amdgcn_exp2f(sc[qt][tt][r] - CSHIFT);
                    sc[qt][tt][r] = p;
                    l_lane[qt] += p;
                }
                pb[qt][tt] = short4v{ f2bf(sc[qt][tt][0]), f2bf(sc[qt][tt][1]),
                                      f2bf(sc[qt][tt][2]), f2bf(sc[qt][tt][3]) };
            }

        #pragma unroll
        for (int td = 0; td < 4; ++td) {
            const short* vr = &Vs[(td * 16 + l15) * 72 + quad * 4];
            #pragma unroll
            for (int tt = 0; tt < 4; ++tt) {
                short4v va = *(const short4v*)(vr + tt * 16);
                #pragma unroll
                for (int qt = 0; qt < 2; ++qt)
                    o_acc[qt][td] = mfma16(va, pb[qt][tt], o_acc[qt][td]);
            }
        }
        __syncthreads();
    }

    #pragma unroll
    for (int qt = 0; qt < 2; ++qt) {
        float l = l_lane[qt];
        l += __shfl_xor(l, 16);
        l += __shfl_xor(l, 32);
        const float inv = 1.0f / l;
        const int qrow = q0 + (w * 2 + qt) * 16 + l15;
        float* op = Ob + (size_t)qrow * D_DIM + quad * 4;
        #pragma unroll
        for (int td = 0; td < 4; ++td) {
            float4v st = { o_acc[qt][td][0] * inv, o_acc[qt][td][1] * inv,
                           o_acc[qt][td][2] * inv, o_acc[qt][td][3] * inv };
            *(float4v*)(op + td * 16) = st;
        }
    }
}

// ---------------- fallback (validated R1 kernel, used if ws too small) ----------------
#define KSTR 72
__global__ __launch_bounds__(256, 2)
void fa_fwd_fb(const float* __restrict__ Q, const float* __restrict__ K,
               const float* __restrict__ V, float* __restrict__ O) {
    __shared__ __align__(16) short Ksf[64 * KSTR];
    __shared__ __align__(16) short Vsf[D_DIM * KSTR];
    __shared__ __align__(16) short Psf[4 * 16 * KSTR];

    const int tid = threadIdx.x, w = tid >> 6, lane = tid & 63;
    const int l15 = lane & 15, quad = lane >> 4;
    const int bh = blockIdx.y, blk = gridDim.x - 1 - blockIdx.x, q0 = blk * 64;
    const float* Qb = Q + (size_t)bh * S_LEN * D_DIM;
    const float* Kb = K + (size_t)bh * S_LEN * D_DIM;
    const float* Vb = V + (size_t)bh * S_LEN * D_DIM;
    float* Ob = O + (size_t)bh * S_LEN * D_DIM;

    short8 qfrag[2];
    {
        const float* qp = Qb + (size_t)(q0 + w * 16 + l15) * D_DIM;
        #pragma unroll
        for (int c = 0; c < 2; ++c) {
            const int d0 = c * 32 + quad * 8;
            float4v a = *(const float4v*)(qp + d0);
            float4v b = *(const float4v*)(qp + d0 + 4);
            qfrag[c][0] = f2bf(a.x * 0.125f); qfrag[c][1] = f2bf(a.y * 0.125f);
            qfrag[c][2] = f2bf(a.z * 0.125f); qfrag[c][3] = f2bf(a.w * 0.125f);
            qfrag[c][4] = f2bf(b.x * 0.125f); qfrag[c][5] = f2bf(b.y * 0.125f);
            qfrag[c][6] = f2bf(b.z * 0.125f); qfrag[c][7] = f2bf(b.w * 0.125f);
        }
    }
    const int crow0 = q0 + w * 16 + quad * 4;
    float m_run[4], l_run[4];
    float4v o_acc[4];
    #pragma unroll
    for (int r = 0; r < 4; ++r) { m_run[r] = -1e30f; l_run[r] = 0.0f; }
    #pragma unroll
    for (int td = 0; td < 4; ++td) o_acc[td] = (float4v)0.0f;
    short* Pw = Psf + w * 16 * KSTR;
    const int n_tiles = blk + 1;

    for (int t = 0; t < n_tiles; ++t) {
        const int kv0 = t * 64;
        __syncthreads();
        #pragma unroll
        for (int i = 0; i < 4; ++i) {
            const int slot = tid + i * 256;
            const int row = slot >> 4, d4 = (slot & 15) << 2;
            float4v k4 = *(const float4v*)(Kb + (size_t)(kv0 + row) * D_DIM + d4);
            short4v ks = { f2bf(k4.x), f2bf(k4.y), f2bf(k4.z), f2bf(k4.w) };
            *(short4v*)&Ksf[row * KSTR + d4] = ks;
            float4v v4 = *(const float4v*)(Vb + (size_t)(kv0 + row) * D_DIM + d4);
            Vsf[(d4 + 0) * KSTR + row] = f2bf(v4.x);
            Vsf[(d4 + 1) * KSTR + row] = f2bf(v4.y);
            Vsf[(d4 + 2) * KSTR + row] = f2bf(v4.z);
            Vsf[(d4 + 3) * KSTR + row] = f2bf(v4.w);
        }
        __syncthreads();
        float4v sc[4];
        #pragma unroll
        for (int tt = 0; tt < 4; ++tt) {
            float4v acc = (float4v)0.0f;
            #pragma unroll
            for (int c = 0; c < 2; ++c) {
                short8 bf = *(const short8*)&Ksf[(tt * 16 + l15) * KSTR + c * 32 + quad * 8];
                acc = __builtin_amdgcn_mfma_f32_16x16x32_bf16(qfrag[c], bf, acc, 0, 0, 0);
            }
            sc[tt] = acc;
        }
        if (t == n_tiles - 1) {
            #pragma unroll
            for (int tt = 0; tt < 4; ++tt) {
                const int col = kv0 + tt * 16 + l15;
                #pragma unroll
                for (int r = 0; r < 4; ++r)
                    if (col > crow0 + r) sc[tt][r] = -1e30f;
            }
        }
        #pragma unroll
        for (int r = 0; r < 4; ++r) {
            float mx = fmaxf(fmaxf(sc[0][r], sc[1][r]), fmaxf(sc[2][r], sc[3][r]));
            #pragma unroll
            for (int off = 1; off <= 8; off <<= 1)
                mx = fmaxf(mx, __shfl_xor(mx, off));
            const float m_new = fmaxf(m_run[r], mx);
            const float alpha = __expf(m_run[r] - m_new);
            m_run[r] = m_new;
            float rs = 0.0f;
            #pragma unroll
            for (int tt = 0; tt < 4; ++tt) {
                float pv = __expf(sc[tt][r] - m_new);
                sc[tt][r] = pv; rs += pv;
            }
            #pragma unroll
            for (int off = 1; off <= 8; off <<= 1)
                rs += __shfl_xor(rs, off);
            l_run[r] = l_run[r] * alpha + rs;
            #pragma unroll
            for (int td = 0; td < 4; ++td) o_acc[td][r] *= alpha;
        }
        #pragma unroll
        for (int tt = 0; tt < 4; ++tt)
            #pragma unroll
            for (int r = 0; r < 4; ++r)
                Pw[(quad * 4 + r) * KSTR + tt * 16 + l15] = f2bf(sc[tt][r]);
        short8 pf[2];
        #pragma unroll
        for (int c = 0; c < 2; ++c)
            pf[c] = *(const short8*)&Pw[l15 * KSTR + c * 32 + quad * 8];
        #pragma unroll
        for (int td = 0; td < 4; ++td)
            #pragma unroll
            for (int c = 0; c < 2; ++c) {
                short8 bv = *(const short8*)&Vsf[(td * 16 + l15) * KSTR + c * 32 + quad * 8];
                o_acc[td] = __builtin_amdgcn_mfma_f32_16x16x32_bf16(pf[c], bv, o_acc[td], 0, 0, 0);
            }
    }
    #pragma unroll
    for (int td = 0; td < 4; ++td)
        #pragma unroll
        for (int r = 0; r < 4; ++r)
            Ob[(size_t)(crow0 + r) * D_DIM + td * 16 + l15] = o_acc[td][r] / l_run[r];
}

extern "C" void kernel_launch(void* const* d_in, const int* in_sizes, int n_in,
                              void* d_out, int out_size, void* d_ws, size_t ws_size,
                              hipStream_t stream) {
    const float* Q = (const float*)d_in[0];
    const float* K = (const float*)d_in[1];
    const float* V = (const float*)d_in[2];
    float* O = (float*)d_out;
    const size_t elems = (size_t)2 * 16 * S_LEN * D_DIM;     // 4,194,304 per matrix
    const size_t needKV = 2 * elems * sizeof(short);          // 16,777,216
    const size_t needSplit = needKV + 8388608 + 262144;       // + OA f32 + lA/lB
    if (ws_size >= needSplit) {
        short* Kbf = (short*)d_ws;
        short* Vt  = Kbf + elems;
        float* OA  = (float*)(Vt + elems);
        float* lab = OA + 2097152;
        prep<<<dim3(32, 32), 256, 0, stream>>>(K, V, Kbf, Vt);
        fa_fwd8<<<dim3(48, 32), 128, 0, stream>>>(Q, Kbf, Vt, O, OA, lab);
        combine<<<dim3(64, 32), 256, 0, stream>>>(O, OA, lab);
    } else if (ws_size >= needKV) {
        short* Kbf = (short*)d_ws;
        short* Vt  = Kbf + elems;
        prep<<<dim3(32, 32), 256, 0, stream>>>(K, V, Kbf, Vt);
        fa_fwd6<<<dim3(32, 32), 128, 0, stream>>>(Q, Kbf, Vt, O);
    } else {
        fa_fwd_fb<<<dim3(32, 32), 256, 0, stream>>>(Q, K, V, O);
    }
}

// Round 4
// 133.406 us; speedup vs baseline: 1.1573x; 1.1573x over previous
//
#include <hip/hip_runtime.h>

// CoreAttention: causal flash attention fwd. B=2,H=16,S=2048,D=64, fp32 in/out.
// R9: CU-load-balanced block mapping, unsplit. R8 post-mortem: wall == busiest
// CU's total tile-iters (all blocks co-resident; grid 32 divides 256 so each
// CU got 4 same-length chains: worst 4x32=128 tiles ~ 66us; split made it
// 96 tiles x higher contention = 76us). Fix: flat 1024-block grid with a
// pair/quadruple-balanced g->(bh,qtile) map: e=g&1, v=(g>>1)&15, b=g>>5;
// base=((b>>3)&1)?31-v:v; qtile=e?31-base:base. Any aligned-4 chunk AND any
// stride-256 set sums to exactly 66 tile-iters (both plausible block->CU
// mappings balanced; XCD round-robin balanced too). Loop = proven R5
// single-buffer global_load_lds staging; compute core unchanged.

#define S_LEN 2048
#define D_DIM 64
#define QSCALE 0.1803368867f          // (1/8) * log2(e)
#define CSHIFT 23.0831206542f         // 16 * log2(e): fixed-shift softmax (shift-invariant)
#define BHSTR 131072                  // shorts per bh plane (2048*64)

typedef __attribute__((ext_vector_type(8))) short short8;
typedef __attribute__((ext_vector_type(4))) short short4v;
typedef __attribute__((ext_vector_type(4))) float float4v;

typedef const __attribute__((address_space(1))) void cg_void;
typedef __attribute__((address_space(3))) void lds_void;

__device__ __forceinline__ short f2bf(float x) {
    union { float f; unsigned u; } c; c.f = x;
    unsigned u = c.u + 0x7fffu + ((c.u >> 16) & 1u);
    return (short)(u >> 16);
}

#if __has_builtin(__builtin_amdgcn_mfma_f32_16x16x16_bf16)
__device__ __forceinline__ float4v mfma16(short4v a, short4v b, float4v c) {
    return __builtin_amdgcn_mfma_f32_16x16x16_bf16(a, b, c, 0, 0, 0);
}
#elif __has_builtin(__builtin_amdgcn_mfma_f32_16x16x16bf16_1k)
__device__ __forceinline__ float4v mfma16(short4v a, short4v b, float4v c) {
    return __builtin_amdgcn_mfma_f32_16x16x16bf16_1k(a, b, c, 0, 0, 0);
}
#else
__device__ __forceinline__ float4v mfma16(short4v a, short4v b, float4v c) {
    float4v d;
    asm("v_mfma_f32_16x16x16_bf16 %0, %1, %2, %3"
        : "=v"(d) : "v"(a), "v"(b), "0"(c));
    return d;
}
#endif

// ---------------- pre-pass: K -> bf16 copy, V -> bf16 transposed (R2 layout) ----------------
#define PVS 80
__global__ __launch_bounds__(256, 4)
void prep(const float* __restrict__ K, const float* __restrict__ V,
          short* __restrict__ Kbf, short* __restrict__ Vt) {
    __shared__ __align__(16) short Vl[D_DIM * PVS];
    const int tid = threadIdx.x;
    const int st  = blockIdx.x;
    const int bh  = blockIdx.y;
    const size_t base = ((size_t)bh * S_LEN + st * 64) * D_DIM;

    #pragma unroll
    for (int i = 0; i < 4; ++i) {
        const int e = (i * 256 + tid) * 4;
        const int kv = e >> 6, d0 = e & 63;
        float4v k4 = *(const float4v*)(K + base + e);
        short4v ks = { f2bf(k4.x), f2bf(k4.y), f2bf(k4.z), f2bf(k4.w) };
        *(short4v*)(Kbf + base + e) = ks;
        float4v v4 = *(const float4v*)(V + base + e);
        Vl[(d0 + 0) * PVS + kv] = f2bf(v4.x);
        Vl[(d0 + 1) * PVS + kv] = f2bf(v4.y);
        Vl[(d0 + 2) * PVS + kv] = f2bf(v4.z);
        Vl[(d0 + 3) * PVS + kv] = f2bf(v4.w);
    }
    __syncthreads();
    const int d = tid >> 2, c = tid & 3;
    short8 a = *(const short8*)&Vl[d * PVS + c * 16];
    short8 b = *(const short8*)&Vl[d * PVS + c * 16 + 8];
    short* dst = Vt + (size_t)bh * BHSTR + (size_t)d * S_LEN + st * 64 + c * 16;
    *(short8*)dst = a;
    *(short8*)(dst + 8) = b;
}

// ---------------- hot kernel (balanced flat grid) ----------------
// g in [0,1024): e=g&1, v=(g>>1)&15, b=g>>5; bh=b;
// base = ((b>>3)&1) ? 31-v : v;  blk = e ? 31-base : base.
// Properties: each (bh,qtile) exactly once; any pair {2u,2u+1} sums to 33
// works; any aligned-4 chunk and any stride-256 quadruple sums to 66 works.
// LDS single buffer: 1152 slots x 16B = 18432 B.
__global__ __launch_bounds__(128, 2)
void fa_fwd9(const float* __restrict__ Q, const short* __restrict__ Kbf,
             const short* __restrict__ Vt, float* __restrict__ O) {
    __shared__ __align__(16) short SB[9216];

    const int tid  = threadIdx.x;       // 0..127, 2 waves
    const int w    = tid >> 6;
    const int lane = tid & 63;
    const int l15  = lane & 15;
    const int quad = lane >> 4;

    const int g    = blockIdx.x;
    const int e    = g & 1;
    const int v    = (g >> 1) & 15;
    const int bh   = g >> 5;                       // [0,32)
    const int base = ((bh >> 3) & 1) ? (31 - v) : v;
    const int blk  = e ? (31 - base) : base;       // q-tile index [0,32)
    const int q0   = blk * 64;

    const float* Qb  = Q + (size_t)bh * S_LEN * D_DIM;
    const short* KbB = Kbf + (size_t)bh * BHSTR;
    const short* VtB = Vt  + (size_t)bh * BHSTR;
    float*       Ob  = O + (size_t)bh * S_LEN * D_DIM;

    // staging: 9 slots/thread (1152 = 9*128). Slot s = i*128 + tid.
    const short* gsrc[9]; int gcoef[9];
    #pragma unroll
    for (int ii = 0; ii < 9; ++ii) {
        const int s = ii * 128 + tid;
        if (s < 576) {
            const int row = s / 9, j = s - row * 9;
            const int j8 = (j == 8) ? 0 : j;        // dup into pad chunk (never read)
            gsrc[ii] = KbB + row * 64 + j8 * 8;
            gcoef[ii] = 4096;
        } else {
            const int ss = s - 576;
            const int row = ss / 9, j = ss - row * 9;
            const int j8 = (j == 8) ? 7 : j;
            gsrc[ii] = VtB + (size_t)row * S_LEN + j8 * 8;
            gcoef[ii] = 64;
        }
    }

    // Q B-frags: B[k=d=quad*8+j(+32c)][n=q=l15], scale log2e/8 folded. 2 q-tiles/wave.
    short8 qfrag[2][2];
    #pragma unroll
    for (int qt = 0; qt < 2; ++qt) {
        const float* qp = Qb + (size_t)(q0 + (w * 2 + qt) * 16 + l15) * D_DIM;
        #pragma unroll
        for (int c = 0; c < 2; ++c) {
            const int d0 = c * 32 + quad * 8;
            float4v a = *(const float4v*)(qp + d0);
            float4v b = *(const float4v*)(qp + d0 + 4);
            qfrag[qt][c][0] = f2bf(a.x * QSCALE); qfrag[qt][c][1] = f2bf(a.y * QSCALE);
            qfrag[qt][c][2] = f2bf(a.z * QSCALE); qfrag[qt][c][3] = f2bf(a.w * QSCALE);
            qfrag[qt][c][4] = f2bf(b.x * QSCALE); qfrag[qt][c][5] = f2bf(b.y * QSCALE);
            qfrag[qt][c][6] = f2bf(b.z * QSCALE); qfrag[qt][c][7] = f2bf(b.w * QSCALE);
        }
    }

    float l_lane[2] = {0.f, 0.f};
    float4v o_acc[2][4];
    #pragma unroll
    for (int qt = 0; qt < 2; ++qt)
        #pragma unroll
        for (int td = 0; td < 4; ++td) o_acc[qt][td] = (float4v)0.0f;

    const short* Ks = SB;
    const short* Vs = SB + 4608;
    const int n_tiles = blk + 1;

    for (int t = 0; t < n_tiles; ++t) {
        __syncthreads();   // prior iteration's ds_reads done; LDS reusable
        #pragma unroll
        for (int ii = 0; ii < 9; ++ii)
            __builtin_amdgcn_global_load_lds(
                (cg_void*)(gsrc[ii] + (size_t)t * gcoef[ii]),
                (lds_void*)&SB[ii * 1024 + w * 512],   // wave-uniform base; HW adds lane*16
                16, 0, 0);
        __syncthreads();   // vmcnt(0) drain -> tile resident

        // S^T = K Q^T: A = K-frag (LDS), B = Q-frag (regs). sc[qt][tt][r]=S^T[kv][q=l15]
        float4v sc[2][4];
        #pragma unroll
        for (int tt = 0; tt < 4; ++tt) {
            const short* kr = &Ks[(tt * 16 + l15) * 72 + quad * 8];
            short8 k0 = *(const short8*)(kr);
            short8 k1 = *(const short8*)(kr + 32);
            #pragma unroll
            for (int qt = 0; qt < 2; ++qt) {
                float4v acc = (float4v)0.0f;
                acc = __builtin_amdgcn_mfma_f32_16x16x32_bf16(k0, qfrag[qt][0], acc, 0, 0, 0);
                acc = __builtin_amdgcn_mfma_f32_16x16x32_bf16(k1, qfrag[qt][1], acc, 0, 0, 0);
                sc[qt][tt] = acc;
            }
        }

        if (t == blk) {   // causal mask, diagonal tile only
            #pragma unroll
            for (int qt = 0; qt < 2; ++qt) {
                const int qrow = q0 + (w * 2 + qt) * 16 + l15;
                #pragma unroll
                for (int tt = 0; tt < 4; ++tt) {
                    const int kv = t * 64 + tt * 16 + quad * 4;
                    #pragma unroll
                    for (int r = 0; r < 4; ++r)
                        if (kv + r > qrow) sc[qt][tt][r] = -3.0e38f;
                }
            }
        }

        // fixed-shift softmax numerator + pack P^T bf16 B-frags (register path)
        short4v pb[2][4];
        #pragma unroll
        for (int qt = 0; qt < 2; ++qt)
            #pragma unroll
            for (int tt = 0; tt < 4; ++tt) {
                #pragma unroll
                for (int r = 0; r < 4; ++r) {
                    float p = __builtin_amdgcn_exp2f(sc[qt][tt][r] - CSHIFT);
                    sc[qt][tt][r] = p;
                    l_lane[qt] += p;
                }
                pb[qt][tt] = short4v{ f2bf(sc[qt][tt][0]), f2bf(sc[qt][tt][1]),
                                      f2bf(sc[qt][tt][2]), f2bf(sc[qt][tt][3]) };
            }

        // O^T += V^T P^T: A = V^T frag (LDS b64), B = P^T (regs). Each va feeds 2 MFMAs.
        #pragma unroll
        for (int td = 0; td < 4; ++td) {
            const short* vr = &Vs[(td * 16 + l15) * 72 + quad * 4];
            #pragma unroll
            for (int tt = 0; tt < 4; ++tt) {
                short4v va = *(const short4v*)(vr + tt * 16);
                #pragma unroll
                for (int qt = 0; qt < 2; ++qt)
                    o_acc[qt][td] = mfma16(va, pb[qt][tt], o_acc[qt][td]);
            }
        }
    }

    // epilogue: reduce l across quads (same column q=l15), scale, store
    #pragma unroll
    for (int qt = 0; qt < 2; ++qt) {
        float l = l_lane[qt];
        l += __shfl_xor(l, 16);
        l += __shfl_xor(l, 32);
        const float inv = 1.0f / l;
        const int qrow = q0 + (w * 2 + qt) * 16 + l15;
        float* op = Ob + (size_t)qrow * D_DIM + quad * 4;
        #pragma unroll
        for (int td = 0; td < 4; ++td) {
            float4v st = { o_acc[qt][td][0] * inv, o_acc[qt][td][1] * inv,
                           o_acc[qt][td][2] * inv, o_acc[qt][td][3] * inv };
            *(float4v*)(op + td * 16) = st;
        }
    }
}

// ---------------- fallback (validated R1 kernel, used if ws too small) ----------------
#define KSTR 72
__global__ __launch_bounds__(256, 2)
void fa_fwd_fb(const float* __restrict__ Q, const float* __restrict__ K,
               const float* __restrict__ V, float* __restrict__ O) {
    __shared__ __align__(16) short Ksf[64 * KSTR];
    __shared__ __align__(16) short Vsf[D_DIM * KSTR];
    __shared__ __align__(16) short Psf[4 * 16 * KSTR];

    const int tid = threadIdx.x, w = tid >> 6, lane = tid & 63;
    const int l15 = lane & 15, quad = lane >> 4;
    const int bh = blockIdx.y, blk = gridDim.x - 1 - blockIdx.x, q0 = blk * 64;
    const float* Qb = Q + (size_t)bh * S_LEN * D_DIM;
    const float* Kb = K + (size_t)bh * S_LEN * D_DIM;
    const float* Vb = V + (size_t)bh * S_LEN * D_DIM;
    float* Ob = O + (size_t)bh * S_LEN * D_DIM;

    short8 qfrag[2];
    {
        const float* qp = Qb + (size_t)(q0 + w * 16 + l15) * D_DIM;
        #pragma unroll
        for (int c = 0; c < 2; ++c) {
            const int d0 = c * 32 + quad * 8;
            float4v a = *(const float4v*)(qp + d0);
            float4v b = *(const float4v*)(qp + d0 + 4);
            qfrag[c][0] = f2bf(a.x * 0.125f); qfrag[c][1] = f2bf(a.y * 0.125f);
            qfrag[c][2] = f2bf(a.z * 0.125f); qfrag[c][3] = f2bf(a.w * 0.125f);
            qfrag[c][4] = f2bf(b.x * 0.125f); qfrag[c][5] = f2bf(b.y * 0.125f);
            qfrag[c][6] = f2bf(b.z * 0.125f); qfrag[c][7] = f2bf(b.w * 0.125f);
        }
    }
    const int crow0 = q0 + w * 16 + quad * 4;
    float m_run[4], l_run[4];
    float4v o_acc[4];
    #pragma unroll
    for (int r = 0; r < 4; ++r) { m_run[r] = -1e30f; l_run[r] = 0.0f; }
    #pragma unroll
    for (int td = 0; td < 4; ++td) o_acc[td] = (float4v)0.0f;
    short* Pw = Psf + w * 16 * KSTR;
    const int n_tiles = blk + 1;

    for (int t = 0; t < n_tiles; ++t) {
        const int kv0 = t * 64;
        __syncthreads();
        #pragma unroll
        for (int i = 0; i < 4; ++i) {
            const int slot = tid + i * 256;
            const int row = slot >> 4, d4 = (slot & 15) << 2;
            float4v k4 = *(const float4v*)(Kb + (size_t)(kv0 + row) * D_DIM + d4);
            short4v ks = { f2bf(k4.x), f2bf(k4.y), f2bf(k4.z), f2bf(k4.w) };
            *(short4v*)&Ksf[row * KSTR + d4] = ks;
            float4v v4 = *(const float4v*)(Vb + (size_t)(kv0 + row) * D_DIM + d4);
            Vsf[(d4 + 0) * KSTR + row] = f2bf(v4.x);
            Vsf[(d4 + 1) * KSTR + row] = f2bf(v4.y);
            Vsf[(d4 + 2) * KSTR + row] = f2bf(v4.z);
            Vsf[(d4 + 3) * KSTR + row] = f2bf(v4.w);
        }
        __syncthreads();
        float4v sc[4];
        #pragma unroll
        for (int tt = 0; tt < 4; ++tt) {
            float4v acc = (float4v)0.0f;
            #pragma unroll
            for (int c = 0; c < 2; ++c) {
                short8 bf = *(const short8*)&Ksf[(tt * 16 + l15) * KSTR + c * 32 + quad * 8];
                acc = __builtin_amdgcn_mfma_f32_16x16x32_bf16(qfrag[c], bf, acc, 0, 0, 0);
            }
            sc[tt] = acc;
        }
        if (t == n_tiles - 1) {
            #pragma unroll
            for (int tt = 0; tt < 4; ++tt) {
                const int col = kv0 + tt * 16 + l15;
                #pragma unroll
                for (int r = 0; r < 4; ++r)
                    if (col > crow0 + r) sc[tt][r] = -1e30f;
            }
        }
        #pragma unroll
        for (int r = 0; r < 4; ++r) {
            float mx = fmaxf(fmaxf(sc[0][r], sc[1][r]), fmaxf(sc[2][r], sc[3][r]));
            #pragma unroll
            for (int off = 1; off <= 8; off <<= 1)
                mx = fmaxf(mx, __shfl_xor(mx, off));
            const float m_new = fmaxf(m_run[r], mx);
            const float alpha = __expf(m_run[r] - m_new);
            m_run[r] = m_new;
            float rs = 0.0f;
            #pragma unroll
            for (int tt = 0; tt < 4; ++tt) {
                float pv = __expf(sc[tt][r] - m_new);
                sc[tt][r] = pv; rs += pv;
            }
            #pragma unroll
            for (int off = 1; off <= 8; off <<= 1)
                rs += __shfl_xor(rs, off);
            l_run[r] = l_run[r] * alpha + rs;
            #pragma unroll
            for (int td = 0; td < 4; ++td) o_acc[td][r] *= alpha;
        }
        #pragma unroll
        for (int tt = 0; tt < 4; ++tt)
            #pragma unroll
            for (int r = 0; r < 4; ++r)
                Pw[(quad * 4 + r) * KSTR + tt * 16 + l15] = f2bf(sc[tt][r]);
        short8 pf[2];
        #pragma unroll
        for (int c = 0; c < 2; ++c)
            pf[c] = *(const short8*)&Pw[l15 * KSTR + c * 32 + quad * 8];
        #pragma unroll
        for (int td = 0; td < 4; ++td)
            #pragma unroll
            for (int c = 0; c < 2; ++c) {
                short8 bv = *(const short8*)&Vsf[(td * 16 + l15) * KSTR + c * 32 + quad * 8];
                o_acc[td] = __builtin_amdgcn_mfma_f32_16x16x32_bf16(pf[c], bv, o_acc[td], 0, 0, 0);
            }
    }
    #pragma unroll
    for (int td = 0; td < 4; ++td)
        #pragma unroll
        for (int r = 0; r < 4; ++r)
            Ob[(size_t)(crow0 + r) * D_DIM + td * 16 + l15] = o_acc[td][r] / l_run[r];
}

extern "C" void kernel_launch(void* const* d_in, const int* in_sizes, int n_in,
                              void* d_out, int out_size, void* d_ws, size_t ws_size,
                              hipStream_t stream) {
    const float* Q = (const float*)d_in[0];
    const float* K = (const float*)d_in[1];
    const float* V = (const float*)d_in[2];
    float* O = (float*)d_out;
    const size_t elems = (size_t)2 * 16 * S_LEN * D_DIM;   // 4,194,304 per matrix
    if (ws_size >= 2 * elems * sizeof(short)) {
        short* Kbf = (short*)d_ws;
        short* Vt  = Kbf + elems;
        prep<<<dim3(32, 32), 256, 0, stream>>>(K, V, Kbf, Vt);
        fa_fwd9<<<dim3(1024, 1), 128, 0, stream>>>(Q, Kbf, Vt, O);
    } else {
        fa_fwd_fb<<<dim3(32, 32), 256, 0, stream>>>(Q, K, V, O);
    }
}